// Round 9
// baseline (599.313 us; speedup 1.0000x reference)
//
#include <hip/hip_runtime.h>
#include <hip/hip_bf16.h>
#include <math.h>

#define DD 256
#define HH 128
#define OO 64

#define EPB 8192          // edges per partition block
#define BKT 512           // nodes per bucket (bucket = idx >> 9)

typedef __attribute__((ext_vector_type(8))) __bf16 bf16x8;
typedef __attribute__((ext_vector_type(4))) __bf16 bf16x4;
typedef __attribute__((ext_vector_type(4))) float f32x4;
typedef __attribute__((ext_vector_type(2))) float f32x2;

__device__ inline float2 bf2_to_f2(unsigned u) {
    float2 r;
    r.x = __uint_as_float(u << 16);
    r.y = __uint_as_float(u & 0xffff0000u);
    return r;
}

// ---------------------------------------------------------------------------
// K0: init degree accumulators (self-loop contributes 1.0 to both branches)
// ---------------------------------------------------------------------------
__global__ void dis_init_kernel(float2* __restrict__ dis, int n) {
    int i = blockIdx.x * blockDim.x + threadIdx.x;
    if (i < n) dis[i] = make_float2(1.0f, 1.0f);
}

// ---------------------------------------------------------------------------
// K1: per-block LDS histogram over coarse buckets (col side only)
// ---------------------------------------------------------------------------
__global__ void part_count_kernel(const int* __restrict__ col,
                                  int e, int nb, int* __restrict__ cnt_col) {
    __shared__ int hc[256];
    int t = threadIdx.x;
    if (t < 256) hc[t] = 0;
    __syncthreads();
    int base = blockIdx.x * EPB;
    int lim  = min(EPB, e - base);
    for (int i = t; i < lim; i += 512)
        atomicAdd(&hc[col[base + i] >> 9], 1);
    __syncthreads();
    if (t < nb) cnt_col[blockIdx.x * nb + t] = hc[t];
}

// ---------------------------------------------------------------------------
// K2a: one block per bucket: scan nblk per-block counts -> bases + total
// ---------------------------------------------------------------------------
__global__ void scan_blocks_kernel(const int* __restrict__ cnt_col,
                                   int* __restrict__ base_col, int* __restrict__ tot_col,
                                   int nblk, int nb) {
    __shared__ int s[256];
    int b = blockIdx.x;
    int t = threadIdx.x;
    int v = (t < nblk) ? cnt_col[(size_t)t * nb + b] : 0;
    s[t] = v;
    __syncthreads();
    for (int off = 1; off < 256; off <<= 1) {
        int u = (t >= off) ? s[t - off] : 0;
        __syncthreads();
        s[t] += u;
        __syncthreads();
    }
    if (t < nblk) base_col[(size_t)t * nb + b] = s[t] - v;
    if (t == 255) tot_col[b] = s[255];
}

// ---------------------------------------------------------------------------
// K2c: each bucket block re-derives its bucket base from totals in LDS,
// adds into per-block bases; emits bb_col and row_ptr[n] = e.
// ---------------------------------------------------------------------------
__global__ void add_bases_kernel(int* __restrict__ base_col,
                                 const int* __restrict__ tot_col,
                                 int* __restrict__ bb_col,
                                 int* __restrict__ row_ptr, int n, int e, int nblk, int nb) {
    __shared__ int s[256];
    __shared__ int bbv;
    int b = blockIdx.x;
    int t = threadIdx.x;
    int v = (t < nb) ? tot_col[t] : 0;
    s[t] = v;
    __syncthreads();
    for (int off = 1; off < 256; off <<= 1) {
        int u = (t >= off) ? s[t - off] : 0;
        __syncthreads();
        s[t] += u;
        __syncthreads();
    }
    if (t == 0) {
        bbv = (b > 0) ? s[b - 1] : 0;
        bb_col[b] = bbv;
    }
    __syncthreads();
    int add = bbv;
    for (int j = t; j < nblk; j += blockDim.x) base_col[(size_t)j * nb + b] += add;
    if (blockIdx.x == 0 && t == 0) row_ptr[n] = e;
}

// ---------------------------------------------------------------------------
// K3: scatter edges into bucket-major temp (col side) via LDS cursors;
// degree accumulation goes straight into dis via L2 float atomics.
// ---------------------------------------------------------------------------
__global__ void part_scatter_kernel(const int* __restrict__ row, const int* __restrict__ col,
                                    const float* __restrict__ ppmi,
                                    const int* __restrict__ base_col,
                                    int4* __restrict__ tmp_col,
                                    float* __restrict__ deg,   // = (float*)dis, {g,p} interleaved
                                    int e, int nb) {
    __shared__ int cc[256];
    int t = threadIdx.x;
    if (t < nb) cc[t] = base_col[blockIdx.x * nb + t];
    __syncthreads();
    int base = blockIdx.x * EPB;
    int lim  = min(EPB, e - base);
    for (int i = t; i < lim; i += 512) {
        int r = row[base + i], c = col[base + i];
        float wf = ppmi[base + i];
        int sc = atomicAdd(&cc[c >> 9], 1);
        tmp_col[sc] = make_int4(c, r, __float_as_int(wf), 0);
        atomicAdd(deg + 2 * (size_t)r, 1.0f);
        atomicAdd(deg + 2 * (size_t)r + 1, wf);
    }
}

// ---------------------------------------------------------------------------
// K3b: finalize dis = rsqrt(deg) in place
// ---------------------------------------------------------------------------
__global__ void dis_fin_kernel(float2* __restrict__ dis, int n) {
    int i = blockIdx.x * blockDim.x + threadIdx.x;
    if (i < n) {
        float2 d = dis[i];
        dis[i] = make_float2(rsqrtf(d.x), rsqrtf(d.y));
    }
}

// ---------------------------------------------------------------------------
// K4: per-col-bucket CSR finalize -> packed edge meta {src, wg, wp, 0}
// ---------------------------------------------------------------------------
__launch_bounds__(512)
__global__ void csr_bucket_kernel(const int4* __restrict__ tmp_col,
                                  const int* __restrict__ bb_col, const int* __restrict__ tot_col,
                                  const float2* __restrict__ dis,
                                  int* __restrict__ row_ptr, int4* __restrict__ csr_meta, int n) {
    __shared__ int hist[BKT], s[BKT], cur[BKT];
    int t = threadIdx.x;   // 512 threads
    hist[t] = 0;
    __syncthreads();
    int b = blockIdx.x;
    int beg = bb_col[b], cnt = tot_col[b];
    for (int i = t; i < cnt; i += BKT) atomicAdd(&hist[tmp_col[beg + i].x & (BKT - 1)], 1);
    __syncthreads();
    int own = hist[t];
    s[t] = own;
    __syncthreads();
    for (int off = 1; off < BKT; off <<= 1) {
        int v = (t >= off) ? s[t - off] : 0;
        __syncthreads();
        s[t] += v;
        __syncthreads();
    }
    int gslot = beg + s[t] - own;
    cur[t] = gslot;
    int gc = (b << 9) + t;
    if (gc < n) row_ptr[gc] = gslot;
    __syncthreads();
    for (int i = t; i < cnt; i += BKT) {
        int4 cell = tmp_col[beg + i];
        int lc = cell.x & (BKT - 1);
        int slot = atomicAdd(&cur[lc], 1);
        int r = cell.y;
        float w = __int_as_float(cell.z);
        float2 d = dis[r];
        csr_meta[slot] = make_int4(r, __float_as_int(d.x), __float_as_int(d.y * w), 0);
    }
}

// ---------------------------------------------------------------------------
// W1+W2 -> B^T split-bf16 prep (fused)
// ---------------------------------------------------------------------------
__global__ void conv_w_kernel(const float* __restrict__ W1, __bf16* __restrict__ B1h,
                              __bf16* __restrict__ B1l,
                              const float* __restrict__ W2, __bf16* __restrict__ B2h,
                              __bf16* __restrict__ B2l) {
    int i = blockIdx.x * blockDim.x + threadIdx.x;
    if (i < DD * HH) {
        int k = i / HH, nn = i % HH;
        float v = W1[i];
        __bf16 h = (__bf16)v;
        B1h[(size_t)nn * DD + k] = h;
        B1l[(size_t)nn * DD + k] = (__bf16)(v - (float)h);
    } else if (i < DD * HH + HH * OO) {
        int j = i - DD * HH;
        int k = j / OO, nn = j % OO;
        float v = W2[j];
        __bf16 h = (__bf16)v;
        B2h[(size_t)nn * HH + k] = h;
        B2l[(size_t)nn * HH + k] = (__bf16)(v - (float)h);
    }
}

// ---------------------------------------------------------------------------
// Split-bf16 MFMA GEMM v3: whole B (split hi/lo) staged in LDS ONCE per block,
// XOR-swizzled on 16B granules. Barrier-free main loop: A streams
// global->regs with depth-1 prefetch; B frags come from LDS.
// 512 threads = 8 waves x 32 rows = 256 rows/block.
// ILV: interleave rows [0,nHalf) and [nHalf,2*nHalf) as C[c][col][{0,1}].
// ---------------------------------------------------------------------------
template<int BNp, int K, bool ILV>
__launch_bounds__(512, 4)
__global__ void mfma_gemm_ldsb_kernel(const float* __restrict__ A,
                                      const __bf16* __restrict__ Bth, const __bf16* __restrict__ Btl,
                                      __bf16* __restrict__ C, int M, int nHalf,
                                      int ncg, int BNtot) {
    constexpr int NT  = BNp / 16;
    constexpr int GPC = K / 8;                 // 16B granules per column
    __shared__ __bf16 Bs[2][BNp][K];           // [hi/lo][col][k], k-granules swizzled

    const int tid = threadIdx.x;
    const int cg  = blockIdx.x % ncg;
    const int rg  = blockIdx.x / ncg;
    const int cb  = cg * BNp;

    // ---- stage all of B into LDS (once) ----
    constexpr int TOT = 2 * BNp * GPC;
    for (int i = tid; i < TOT; i += 512) {
        int arr = i / (BNp * GPC);
        int rem = i - arr * (BNp * GPC);
        int c   = rem / GPC;
        int g   = rem - c * GPC;
        const __bf16* src = (arr ? Btl : Bth) + (size_t)(cb + c) * K + g * 8;
        uint4 v = *(const uint4*)src;
        *(uint4*)&Bs[arr][c][(g ^ (c & 7)) * 8] = v;
    }
    __syncthreads();   // the only barrier

    const int wave = tid >> 6;
    const int lane = tid & 63;
    const int quad = lane >> 4;
    const int l16  = lane & 15;
    const int row0 = rg * 256 + wave * 32;
    if (row0 >= M) return;

    f32x4 acc[2][NT] = {};
    const float* ap0 = A + (size_t)(row0 + l16) * K + quad * 8;
    const float* ap1 = A + (size_t)(row0 + 16 + l16) * K + quad * 8;

    float4 a0[2][2];
    a0[0][0] = *(const float4*)ap0;  a0[0][1] = *(const float4*)(ap0 + 4);
    a0[1][0] = *(const float4*)ap1;  a0[1][1] = *(const float4*)(ap1 + 4);

    for (int k0 = 0; k0 < K; k0 += 32) {
        // prefetch next K-step's A (sequential addresses, issued early)
        float4 a1[2][2];
        if (k0 + 32 < K) {
            a1[0][0] = *(const float4*)(ap0 + k0 + 32);
            a1[0][1] = *(const float4*)(ap0 + k0 + 36);
            a1[1][0] = *(const float4*)(ap1 + k0 + 32);
            a1[1][1] = *(const float4*)(ap1 + k0 + 36);
        }
        // B fragments from LDS (swizzled; ~2-way conflicts = free)
        const int g0 = (k0 >> 3) + quad;
        bf16x8 bh[NT], bl[NT];
#pragma unroll
        for (int j = 0; j < NT; ++j) {
            int c  = j * 16 + l16;
            int gg = (g0 ^ (c & 7)) * 8;
            bh[j] = *(const bf16x8*)&Bs[0][c][gg];
            bl[j] = *(const bf16x8*)&Bs[1][c][gg];
        }
#pragma unroll
        for (int i = 0; i < 2; ++i) {
            float vv0 = a0[i][0].x, vv1 = a0[i][0].y, vv2 = a0[i][0].z, vv3 = a0[i][0].w;
            float vv4 = a0[i][1].x, vv5 = a0[i][1].y, vv6 = a0[i][1].z, vv7 = a0[i][1].w;
            __bf16 h0 = (__bf16)vv0, h1 = (__bf16)vv1, h2 = (__bf16)vv2, h3 = (__bf16)vv3;
            __bf16 h4 = (__bf16)vv4, h5 = (__bf16)vv5, h6 = (__bf16)vv6, h7 = (__bf16)vv7;
            bf16x8 ah = (bf16x8){h0, h1, h2, h3, h4, h5, h6, h7};
            bf16x8 al = (bf16x8){(__bf16)(vv0 - (float)h0), (__bf16)(vv1 - (float)h1),
                                 (__bf16)(vv2 - (float)h2), (__bf16)(vv3 - (float)h3),
                                 (__bf16)(vv4 - (float)h4), (__bf16)(vv5 - (float)h5),
                                 (__bf16)(vv6 - (float)h6), (__bf16)(vv7 - (float)h7)};
#pragma unroll
            for (int j = 0; j < NT; ++j) {
                acc[i][j] = __builtin_amdgcn_mfma_f32_16x16x32_bf16(ah, bh[j], acc[i][j], 0, 0, 0);
                acc[i][j] = __builtin_amdgcn_mfma_f32_16x16x32_bf16(ah, bl[j], acc[i][j], 0, 0, 0);
                acc[i][j] = __builtin_amdgcn_mfma_f32_16x16x32_bf16(al, bh[j], acc[i][j], 0, 0, 0);
            }
        }
        if (k0 + 32 < K) {
            a0[0][0] = a1[0][0]; a0[0][1] = a1[0][1];
            a0[1][0] = a1[1][0]; a0[1][1] = a1[1][1];
        }
    }

#pragma unroll
    for (int i = 0; i < 2; ++i) {
#pragma unroll
        for (int rg2 = 0; rg2 < 4; ++rg2) {
            int gr = row0 + i * 16 + quad * 4 + rg2;
            if constexpr (ILV) {
                int s = (gr >= nHalf) ? 1 : 0;
                size_t base = (size_t)(gr - s * nHalf) * (BNtot * 2) + s;
#pragma unroll
                for (int j = 0; j < NT; ++j)
                    C[base + (size_t)(cb + j * 16 + l16) * 2] = (__bf16)acc[i][j][rg2];
            } else {
#pragma unroll
                for (int j = 0; j < NT; ++j)
                    C[(size_t)gr * BNtot + cb + j * 16 + l16] = (__bf16)acc[i][j][rg2];
            }
        }
    }
}

// ---------------------------------------------------------------------------
// Layer-1 pull aggregation v3: one wave per node; wave-uniform meta/bounds
// readfirstlane'd to the scalar path; gather = saddr + lane*4. No LDS.
// ---------------------------------------------------------------------------
__global__ void agg1_pull_kernel(const int* __restrict__ row_ptr, const int4* __restrict__ meta,
                                 const __bf16* __restrict__ hw1,
                                 const float2* __restrict__ dis,
                                 const float* __restrict__ b1,
                                 float* __restrict__ g_out, float* __restrict__ p_out, int n) {
    const int wave = threadIdx.x >> 6;
    const int lane = threadIdx.x & 63;
    int c = blockIdx.x * 4 + wave;
    if (c >= n) return;
    const int cu  = __builtin_amdgcn_readfirstlane(c);
    const int beg = __builtin_amdgcn_readfirstlane(row_ptr[cu]);
    const int end = __builtin_amdgcn_readfirstlane(row_ptr[cu + 1]);
    float sgx = 0.f, sgy = 0.f, spx = 0.f, spy = 0.f;
    int t = beg;
    for (; t + 8 <= end; t += 8) {
        int4 m[8];
#pragma unroll
        for (int q = 0; q < 8; ++q) m[q] = meta[t + q];
        unsigned u[8];
#pragma unroll
        for (int q = 0; q < 8; ++q) {
            const unsigned* rp = (const unsigned*)(hw1 + ((size_t)(unsigned)m[q].x << 7));
            u[q] = rp[lane];
        }
#pragma unroll
        for (int q = 0; q < 8; ++q) {
            float2 h = bf2_to_f2(u[q]);
            float wg = __uint_as_float((unsigned)m[q].y);
            float wp = __uint_as_float((unsigned)m[q].z);
            sgx += wg * h.x; sgy += wg * h.y;
            spx += wp * h.x; spy += wp * h.y;
        }
    }
    if (t + 4 <= end) {
        int4 m[4];
#pragma unroll
        for (int q = 0; q < 4; ++q) m[q] = meta[t + q];
        unsigned u[4];
#pragma unroll
        for (int q = 0; q < 4; ++q) {
            const unsigned* rp = (const unsigned*)(hw1 + ((size_t)(unsigned)m[q].x << 7));
            u[q] = rp[lane];
        }
#pragma unroll
        for (int q = 0; q < 4; ++q) {
            float2 h = bf2_to_f2(u[q]);
            float wg = __uint_as_float((unsigned)m[q].y);
            float wp = __uint_as_float((unsigned)m[q].z);
            sgx += wg * h.x; sgy += wg * h.y;
            spx += wp * h.x; spy += wp * h.y;
        }
        t += 4;
    }
    for (; t < end; ++t) {
        int4 m0 = meta[t];
        const unsigned* rp = (const unsigned*)(hw1 + ((size_t)(unsigned)m0.x << 7));
        float2 h0 = bf2_to_f2(rp[lane]);
        float wg0 = __uint_as_float((unsigned)m0.y);
        float wp0 = __uint_as_float((unsigned)m0.z);
        sgx += wg0 * h0.x; sgy += wg0 * h0.y;
        spx += wp0 * h0.x; spy += wp0 * h0.y;
    }

    const int f2 = lane * 2;
    float2 d = dis[c];
    size_t idx = ((size_t)c << 7) + f2;
    float2 hs = bf2_to_f2(*(const unsigned*)(hw1 + idx));
    float2 bv = *(const float2*)(b1 + f2);
    float gx = d.x * sgx + d.x * d.x * hs.x + bv.x;
    float gy = d.x * sgy + d.x * d.x * hs.y + bv.y;
    float px = d.y * spx + d.y * d.y * hs.x + bv.x;
    float py = d.y * spy + d.y * d.y * hs.y + bv.y;
    f32x2 go, po;
    go[0] = gx > 0.f ? gx : 0.f;  go[1] = gy > 0.f ? gy : 0.f;
    po[0] = px > 0.f ? px : 0.f;  po[1] = py > 0.f ? py : 0.f;
    __builtin_nontemporal_store(go, (f32x2*)(g_out + idx));
    __builtin_nontemporal_store(po, (f32x2*)(p_out + idx));
}

// ---------------------------------------------------------------------------
// Layer-2 pull aggregation v3 + self-loop + bias + softmax gate.
// hw2i layout: [n][64][2] bf16; scalarized meta as agg1.
// ---------------------------------------------------------------------------
__global__ void agg2_final_kernel(const int* __restrict__ row_ptr, const int4* __restrict__ meta,
                                  const __bf16* __restrict__ hw2i,
                                  const float2* __restrict__ dis,
                                  const float* __restrict__ b2,
                                  const float* __restrict__ dense_w, const float* __restrict__ dense_b,
                                  float* __restrict__ out, int n) {
    const int wave = threadIdx.x >> 6;
    const int f    = threadIdx.x & 63;
    int c = blockIdx.x * 4 + wave;
    if (c >= n) return;
    const int cu  = __builtin_amdgcn_readfirstlane(c);
    const int beg = __builtin_amdgcn_readfirstlane(row_ptr[cu]);
    const int end = __builtin_amdgcn_readfirstlane(row_ptr[cu + 1]);
    float sg = 0.f, sp = 0.f;
    int t = beg;
    for (; t + 8 <= end; t += 8) {
        int4 m[8];
#pragma unroll
        for (int q = 0; q < 8; ++q) m[q] = meta[t + q];
        unsigned u[8];
#pragma unroll
        for (int q = 0; q < 8; ++q) {
            const unsigned* rp = (const unsigned*)(hw2i + ((size_t)(unsigned)m[q].x << 7));
            u[q] = rp[f];
        }
#pragma unroll
        for (int q = 0; q < 8; ++q) {
            float2 g0 = bf2_to_f2(u[q]);
            sg += __uint_as_float((unsigned)m[q].y) * g0.x;
            sp += __uint_as_float((unsigned)m[q].z) * g0.y;
        }
    }
    if (t + 4 <= end) {
        int4 m[4];
#pragma unroll
        for (int q = 0; q < 4; ++q) m[q] = meta[t + q];
        unsigned u[4];
#pragma unroll
        for (int q = 0; q < 4; ++q) {
            const unsigned* rp = (const unsigned*)(hw2i + ((size_t)(unsigned)m[q].x << 7));
            u[q] = rp[f];
        }
#pragma unroll
        for (int q = 0; q < 4; ++q) {
            float2 g0 = bf2_to_f2(u[q]);
            sg += __uint_as_float((unsigned)m[q].y) * g0.x;
            sp += __uint_as_float((unsigned)m[q].z) * g0.y;
        }
        t += 4;
    }
    for (; t < end; ++t) {
        int4 m0 = meta[t];
        const unsigned* rp = (const unsigned*)(hw2i + ((size_t)(unsigned)m0.x << 7));
        float2 g0 = bf2_to_f2(rp[f]);
        sg += __uint_as_float((unsigned)m0.y) * g0.x;
        sp += __uint_as_float((unsigned)m0.z) * g0.y;
    }

    const int f2 = f * 2;
    float2 d = dis[c];
    float2 gps = bf2_to_f2(*(const unsigned*)(hw2i + ((size_t)c << 7) + f2));
    float bb = b2[f];
    float gv = d.x * sg + d.x * d.x * gps.x + bb;
    float pv = d.y * sp + d.y * d.y * gps.y + bb;
    float dwv = dense_w[f];
    float lg = gv * dwv, lp = pv * dwv;
#pragma unroll
    for (int off = 32; off > 0; off >>= 1) {
        lg += __shfl_xor(lg, off, 64);
        lp += __shfl_xor(lp, off, 64);
    }
    lg += dense_b[0];
    lp += dense_b[0];
    float m  = fmaxf(lg, lp);
    float eg = expf(lg - m), ep = expf(lp - m);
    float wgt = eg / (eg + ep);
    __builtin_nontemporal_store(wgt * gv + (1.0f - wgt) * pv, out + (size_t)c * OO + f);
}

// ---------------------------------------------------------------------------
extern "C" void kernel_launch(void* const* d_in, const int* in_sizes, int n_in,
                              void* d_out, int out_size, void* d_ws, size_t ws_size,
                              hipStream_t stream) {
    const float* x    = (const float*)d_in[0];
    const int*   ei   = (const int*)d_in[1];
    const float* ppmi = (const float*)d_in[2];
    const float* W1   = (const float*)d_in[3];
    const float* b1   = (const float*)d_in[4];
    const float* W2   = (const float*)d_in[5];
    const float* b2   = (const float*)d_in[6];
    const float* dw   = (const float*)d_in[7];
    const float* db   = (const float*)d_in[8];
    float* out = (float*)d_out;

    const int n = in_sizes[0] / DD;       // 100000
    const int e = in_sizes[2];            // 1600000
    const int* row = ei;
    const int* col = ei + e;

    const int nb   = (n + BKT - 1) / BKT;   // buckets (<=256 required)
    const int nblk = (e + EPB - 1) / EPB;   // partition blocks (<=256 required)

    // ---- workspace layout ----
    float* ws      = (float*)d_ws;
    float2* dis    = (float2*)ws;                     // n float2 (deg accum -> rsqrt in place)
    __bf16* hw1    = (__bf16*)(ws + 2 * (size_t)n);   // n*128 bf16 (aliased as hw2i [n][64][2])
    float* g1      = (float*)(hw1 + (size_t)n * HH);  // n*128 f32 (tmp_col aliases: int4[e])
    float* p1      = g1 + (size_t)n * HH;             // n*128 f32
    int4* csr_meta = (int4*)(p1 + (size_t)n * HH);    // e int4 {src, wg, wp, 0}
    __bf16* bt1h   = (__bf16*)(csr_meta + e);         // DD*HH
    __bf16* bt1l   = bt1h + (size_t)DD * HH;
    __bf16* bt2h   = bt1l + (size_t)DD * HH;          // HH*OO
    __bf16* bt2l   = bt2h + (size_t)HH * OO;
    int* row_ptr   = (int*)(bt2l + (size_t)HH * OO);  // n+1
    int* cnt_col   = row_ptr + (n + 1);               // nblk*nb
    int* base_col  = cnt_col + (size_t)nblk * nb;     // nblk*nb
    int* bb_col    = base_col + (size_t)nblk * nb;    // nb
    int* tot_col   = bb_col + nb;                     // nb
    int4* tmp_col  = (int4*)g1;                       // e (alias, dead before agg1 writes g1)
    __bf16* hw2i   = hw1;                             // [n][64][2] bf16 (hw1 dead after agg1)

    const int T = 256;

    // ---- partition pipeline (col side only; degrees via L2 atomics) ----
    dis_init_kernel<<<(n + 1023) / 1024, 1024, 0, stream>>>(dis, n);
    part_count_kernel<<<nblk, 512, 0, stream>>>(col, e, nb, cnt_col);
    scan_blocks_kernel<<<nb, T, 0, stream>>>(cnt_col, base_col, tot_col, nblk, nb);
    add_bases_kernel<<<nb, T, 0, stream>>>(base_col, tot_col, bb_col, row_ptr, n, e, nblk, nb);
    part_scatter_kernel<<<nblk, 512, 0, stream>>>(row, col, ppmi, base_col,
                                                  tmp_col, (float*)dis, e, nb);
    dis_fin_kernel<<<(n + 1023) / 1024, 1024, 0, stream>>>(dis, n);
    csr_bucket_kernel<<<nb, BKT, 0, stream>>>(tmp_col, bb_col, tot_col, dis,
                                              row_ptr, csr_meta, n);

    // ---- weight prep (fused) ----
    conv_w_kernel<<<(DD * HH + HH * OO + T - 1) / T, T, 0, stream>>>(W1, bt1h, bt1l,
                                                                     W2, bt2h, bt2l);

    // ---- network ----
    {
        int nrg = (n + 255) / 256;             // row-groups, 2 col-groups
        mfma_gemm_ldsb_kernel<64, 256, false><<<nrg * 2, 512, 0, stream>>>(
            x, bt1h, bt1l, hw1, n, 0, 2, HH);
    }
    agg1_pull_kernel<<<(n + 3) / 4, 256, 0, stream>>>(row_ptr, csr_meta, hw1, dis, b1, g1, p1, n);
    {
        int nrg = (2 * n + 255) / 256;         // row-groups, 1 col-group
        mfma_gemm_ldsb_kernel<64, 128, true><<<nrg, 512, 0, stream>>>(
            g1, bt2h, bt2l, hw2i, 2 * n, n, 1, OO);
    }
    agg2_final_kernel<<<(n + 3) / 4, 256, 0, stream>>>(row_ptr, csr_meta, hw2i, dis,
                                                      b2, dw, db, out, n);
}

// Round 10
// 500.347 us; speedup vs baseline: 1.1978x; 1.1978x over previous
//
#include <hip/hip_runtime.h>
#include <hip/hip_bf16.h>
#include <math.h>

#define DD 256
#define HH 128
#define OO 64

#define EPB 8192          // edges per partition block
#define BKT 512           // nodes per bucket (bucket = idx >> 9)
#define AWIN 512          // agg LDS meta window (edges)

typedef __attribute__((ext_vector_type(8))) __bf16 bf16x8;
typedef __attribute__((ext_vector_type(4))) __bf16 bf16x4;
typedef __attribute__((ext_vector_type(4))) float f32x4;
typedef __attribute__((ext_vector_type(2))) float f32x2;
typedef __attribute__((ext_vector_type(4))) int i32x4;

__device__ inline float2 bf2_to_f2(unsigned u) {
    float2 r;
    r.x = __uint_as_float(u << 16);
    r.y = __uint_as_float(u & 0xffff0000u);
    return r;
}

// ---------------------------------------------------------------------------
// K1: per-block LDS histograms over coarse buckets (both col and row sides)
// ---------------------------------------------------------------------------
__global__ void part_count_kernel(const int* __restrict__ row, const int* __restrict__ col,
                                  int e, int nb,
                                  int* __restrict__ cnt_col, int* __restrict__ cnt_row) {
    __shared__ int hc[256], hr[256];
    int t = threadIdx.x;
    if (t < 256) { hc[t] = 0; hr[t] = 0; }
    __syncthreads();
    int base = blockIdx.x * EPB;
    int lim  = min(EPB, e - base);
    for (int i = t; i < lim; i += 512) {
        atomicAdd(&hc[col[base + i] >> 9], 1);
        atomicAdd(&hr[row[base + i] >> 9], 1);
    }
    __syncthreads();
    if (t < nb) {
        cnt_col[blockIdx.x * nb + t] = hc[t];
        cnt_row[blockIdx.x * nb + t] = hr[t];
    }
}

// ---------------------------------------------------------------------------
// K2a: one block per (side,bucket): scan nblk per-block counts -> bases+total
// ---------------------------------------------------------------------------
__global__ void scan_blocks_kernel(const int* __restrict__ cnt_col, const int* __restrict__ cnt_row,
                                   int* __restrict__ base_col, int* __restrict__ base_row,
                                   int* __restrict__ tot_col, int* __restrict__ tot_row,
                                   int nblk, int nb) {
    __shared__ int s[256];
    int side = (blockIdx.x >= (unsigned)nb) ? 1 : 0;
    int b = blockIdx.x - side * nb;
    const int* cnt = side ? cnt_row : cnt_col;
    int* base = side ? base_row : base_col;
    int* tot  = side ? tot_row  : tot_col;
    int t = threadIdx.x;
    int v = (t < nblk) ? cnt[(size_t)t * nb + b] : 0;
    s[t] = v;
    __syncthreads();
    for (int off = 1; off < 256; off <<= 1) {
        int u = (t >= off) ? s[t - off] : 0;
        __syncthreads();
        s[t] += u;
        __syncthreads();
    }
    if (t < nblk) base[(size_t)t * nb + b] = s[t] - v;
    if (t == 255) tot[b] = s[255];
}

// ---------------------------------------------------------------------------
// K2c: each (side,bucket) block re-derives its bucket base from totals in LDS,
// adds into per-block bases; emits bb_col/bb_row and row_ptr[n] = e.
// ---------------------------------------------------------------------------
__global__ void add_bases_kernel(int* __restrict__ base_col, int* __restrict__ base_row,
                                 const int* __restrict__ tot_col, const int* __restrict__ tot_row,
                                 int* __restrict__ bb_col, int* __restrict__ bb_row,
                                 int* __restrict__ row_ptr, int n, int e, int nblk, int nb) {
    __shared__ int s[256];
    __shared__ int bbv;
    int side = (blockIdx.x >= (unsigned)nb) ? 1 : 0;
    int b = blockIdx.x - side * nb;
    const int* tot = side ? tot_row : tot_col;
    int* base = side ? base_row : base_col;
    int t = threadIdx.x;
    int v = (t < nb) ? tot[t] : 0;
    s[t] = v;
    __syncthreads();
    for (int off = 1; off < 256; off <<= 1) {
        int u = (t >= off) ? s[t - off] : 0;
        __syncthreads();
        s[t] += u;
        __syncthreads();
    }
    if (t == 0) {
        bbv = (b > 0) ? s[b - 1] : 0;
        (side ? bb_row : bb_col)[b] = bbv;
    }
    __syncthreads();
    int add = bbv;
    for (int j = t; j < nblk; j += blockDim.x) base[(size_t)j * nb + b] += add;
    if (blockIdx.x == 0 && t == 0) row_ptr[n] = e;
}

// ---------------------------------------------------------------------------
// K3: scatter edges into bucket-major temps via LDS cursors (512 threads)
// ---------------------------------------------------------------------------
__global__ void part_scatter_kernel(const int* __restrict__ row, const int* __restrict__ col,
                                    const float* __restrict__ ppmi,
                                    const int* __restrict__ base_col, const int* __restrict__ base_row,
                                    int4* __restrict__ tmp_col, int2* __restrict__ tmp_row,
                                    int e, int nb) {
    __shared__ int cc[256], cr[256];
    int t = threadIdx.x;
    if (t < nb) {
        cc[t] = base_col[blockIdx.x * nb + t];
        cr[t] = base_row[blockIdx.x * nb + t];
    }
    __syncthreads();
    int base = blockIdx.x * EPB;
    int lim  = min(EPB, e - base);
    for (int i = t; i < lim; i += 512) {
        int r = row[base + i], c = col[base + i];
        int w = __float_as_int(ppmi[base + i]);
        int sc = atomicAdd(&cc[c >> 9], 1);
        tmp_col[sc] = make_int4(c, r, w, 0);
        int sr = atomicAdd(&cr[r >> 9], 1);
        tmp_row[sr] = make_int2(r, w);
    }
}

// ---------------------------------------------------------------------------
// K4b: per-row-bucket degree accumulation in LDS -> dis (float2: {g, p})
// ---------------------------------------------------------------------------
__global__ void deg_bucket_kernel(const int2* __restrict__ tmp_row,
                                  const int* __restrict__ bb_row, const int* __restrict__ tot_row,
                                  float2* __restrict__ dis, int n) {
    __shared__ float dg[BKT], dp[BKT];
    int t = threadIdx.x;   // 512
    dg[t] = 1.0f; dp[t] = 1.0f;   // self-loop
    __syncthreads();
    int b = blockIdx.x;
    int beg = bb_row[b], cnt = tot_row[b];
    for (int i = t; i < cnt; i += 512) {
        int2 cell = tmp_row[beg + i];
        int lr = cell.x & (BKT - 1);
        atomicAdd(&dg[lr], 1.0f);
        atomicAdd(&dp[lr], __int_as_float(cell.y));
    }
    __syncthreads();
    int g = (b << 9) + t;
    if (g < n) dis[g] = make_float2(rsqrtf(dg[t]), rsqrtf(dp[t]));
}

// ---------------------------------------------------------------------------
// K4: per-col-bucket CSR finalize -> packed edge meta {src, wg, wp, 0}
// ---------------------------------------------------------------------------
__launch_bounds__(512)
__global__ void csr_bucket_kernel(const int4* __restrict__ tmp_col,
                                  const int* __restrict__ bb_col, const int* __restrict__ tot_col,
                                  const float2* __restrict__ dis,
                                  int* __restrict__ row_ptr, int4* __restrict__ csr_meta, int n) {
    __shared__ int hist[BKT], s[BKT], cur[BKT];
    int t = threadIdx.x;   // 512 threads
    hist[t] = 0;
    __syncthreads();
    int b = blockIdx.x;
    int beg = bb_col[b], cnt = tot_col[b];
    for (int i = t; i < cnt; i += BKT) atomicAdd(&hist[tmp_col[beg + i].x & (BKT - 1)], 1);
    __syncthreads();
    int own = hist[t];
    s[t] = own;
    __syncthreads();
    for (int off = 1; off < BKT; off <<= 1) {
        int v = (t >= off) ? s[t - off] : 0;
        __syncthreads();
        s[t] += v;
        __syncthreads();
    }
    int gslot = beg + s[t] - own;
    cur[t] = gslot;
    int gc = (b << 9) + t;
    if (gc < n) row_ptr[gc] = gslot;
    __syncthreads();
    for (int i = t; i < cnt; i += BKT) {
        int4 cell = tmp_col[beg + i];
        int lc = cell.x & (BKT - 1);
        int slot = atomicAdd(&cur[lc], 1);
        int r = cell.y;
        float w = __int_as_float(cell.z);
        float2 d = dis[r];
        csr_meta[slot] = make_int4(r, __float_as_int(d.x), __float_as_int(d.y * w), 0);
    }
}

// ---------------------------------------------------------------------------
// W1+W2 -> B^T split-bf16 prep (fused)
// ---------------------------------------------------------------------------
__global__ void conv_w_kernel(const float* __restrict__ W1, __bf16* __restrict__ B1h,
                              __bf16* __restrict__ B1l,
                              const float* __restrict__ W2, __bf16* __restrict__ B2h,
                              __bf16* __restrict__ B2l) {
    int i = blockIdx.x * blockDim.x + threadIdx.x;
    if (i < DD * HH) {
        int k = i / HH, nn = i % HH;
        float v = W1[i];
        __bf16 h = (__bf16)v;
        B1h[(size_t)nn * DD + k] = h;
        B1l[(size_t)nn * DD + k] = (__bf16)(v - (float)h);
    } else if (i < DD * HH + HH * OO) {
        int j = i - DD * HH;
        int k = j / OO, nn = j % OO;
        float v = W2[j];
        __bf16 h = (__bf16)v;
        B2h[(size_t)nn * HH + k] = h;
        B2l[(size_t)nn * HH + k] = (__bf16)(v - (float)h);
    }
}

// ---------------------------------------------------------------------------
// Split-bf16 MFMA GEMM v3: whole B (split hi/lo) staged in LDS ONCE per block,
// XOR-swizzled on 16B granules. Barrier-free main loop: A streams
// global->regs with depth-1 prefetch; B frags come from LDS.
// 512 threads = 8 waves x 32 rows = 256 rows/block.
// ILV: interleave rows [0,nHalf) and [nHalf,2*nHalf) as C[c][col][{0,1}].
// ---------------------------------------------------------------------------
template<int BNp, int K, bool ILV>
__launch_bounds__(512, 4)
__global__ void mfma_gemm_ldsb_kernel(const float* __restrict__ A,
                                      const __bf16* __restrict__ Bth, const __bf16* __restrict__ Btl,
                                      __bf16* __restrict__ C, int M, int nHalf,
                                      int ncg, int BNtot) {
    constexpr int NT  = BNp / 16;
    constexpr int GPC = K / 8;                 // 16B granules per column
    __shared__ __bf16 Bs[2][BNp][K];           // [hi/lo][col][k], k-granules swizzled

    const int tid = threadIdx.x;
    const int cg  = blockIdx.x % ncg;
    const int rg  = blockIdx.x / ncg;
    const int cb  = cg * BNp;

    // ---- stage all of B into LDS (once) ----
    constexpr int TOT = 2 * BNp * GPC;
    for (int i = tid; i < TOT; i += 512) {
        int arr = i / (BNp * GPC);
        int rem = i - arr * (BNp * GPC);
        int c   = rem / GPC;
        int g   = rem - c * GPC;
        const __bf16* src = (arr ? Btl : Bth) + (size_t)(cb + c) * K + g * 8;
        uint4 v = *(const uint4*)src;
        *(uint4*)&Bs[arr][c][(g ^ (c & 7)) * 8] = v;
    }
    __syncthreads();   // the only barrier

    const int wave = tid >> 6;
    const int lane = tid & 63;
    const int quad = lane >> 4;
    const int l16  = lane & 15;
    const int row0 = rg * 256 + wave * 32;
    if (row0 >= M) return;

    f32x4 acc[2][NT] = {};
    const float* ap0 = A + (size_t)(row0 + l16) * K + quad * 8;
    const float* ap1 = A + (size_t)(row0 + 16 + l16) * K + quad * 8;

    float4 a0[2][2];
    a0[0][0] = *(const float4*)ap0;  a0[0][1] = *(const float4*)(ap0 + 4);
    a0[1][0] = *(const float4*)ap1;  a0[1][1] = *(const float4*)(ap1 + 4);

    for (int k0 = 0; k0 < K; k0 += 32) {
        // prefetch next K-step's A (sequential addresses, issued early)
        float4 a1[2][2];
        if (k0 + 32 < K) {
            a1[0][0] = *(const float4*)(ap0 + k0 + 32);
            a1[0][1] = *(const float4*)(ap0 + k0 + 36);
            a1[1][0] = *(const float4*)(ap1 + k0 + 32);
            a1[1][1] = *(const float4*)(ap1 + k0 + 36);
        }
        // B fragments from LDS (swizzled; ~2-way conflicts = free)
        const int g0 = (k0 >> 3) + quad;
        bf16x8 bh[NT], bl[NT];
#pragma unroll
        for (int j = 0; j < NT; ++j) {
            int c  = j * 16 + l16;
            int gg = (g0 ^ (c & 7)) * 8;
            bh[j] = *(const bf16x8*)&Bs[0][c][gg];
            bl[j] = *(const bf16x8*)&Bs[1][c][gg];
        }
#pragma unroll
        for (int i = 0; i < 2; ++i) {
            float vv0 = a0[i][0].x, vv1 = a0[i][0].y, vv2 = a0[i][0].z, vv3 = a0[i][0].w;
            float vv4 = a0[i][1].x, vv5 = a0[i][1].y, vv6 = a0[i][1].z, vv7 = a0[i][1].w;
            __bf16 h0 = (__bf16)vv0, h1 = (__bf16)vv1, h2 = (__bf16)vv2, h3 = (__bf16)vv3;
            __bf16 h4 = (__bf16)vv4, h5 = (__bf16)vv5, h6 = (__bf16)vv6, h7 = (__bf16)vv7;
            bf16x8 ah = (bf16x8){h0, h1, h2, h3, h4, h5, h6, h7};
            bf16x8 al = (bf16x8){(__bf16)(vv0 - (float)h0), (__bf16)(vv1 - (float)h1),
                                 (__bf16)(vv2 - (float)h2), (__bf16)(vv3 - (float)h3),
                                 (__bf16)(vv4 - (float)h4), (__bf16)(vv5 - (float)h5),
                                 (__bf16)(vv6 - (float)h6), (__bf16)(vv7 - (float)h7)};
#pragma unroll
            for (int j = 0; j < NT; ++j) {
                acc[i][j] = __builtin_amdgcn_mfma_f32_16x16x32_bf16(ah, bh[j], acc[i][j], 0, 0, 0);
                acc[i][j] = __builtin_amdgcn_mfma_f32_16x16x32_bf16(ah, bl[j], acc[i][j], 0, 0, 0);
                acc[i][j] = __builtin_amdgcn_mfma_f32_16x16x32_bf16(al, bh[j], acc[i][j], 0, 0, 0);
            }
        }
        if (k0 + 32 < K) {
            a0[0][0] = a1[0][0]; a0[0][1] = a1[0][1];
            a0[1][0] = a1[1][0]; a0[1][1] = a1[1][1];
        }
    }

#pragma unroll
    for (int i = 0; i < 2; ++i) {
#pragma unroll
        for (int rg2 = 0; rg2 < 4; ++rg2) {
            int gr = row0 + i * 16 + quad * 4 + rg2;
            if constexpr (ILV) {
                int s = (gr >= nHalf) ? 1 : 0;
                size_t base = (size_t)(gr - s * nHalf) * (BNtot * 2) + s;
#pragma unroll
                for (int j = 0; j < NT; ++j)
                    C[base + (size_t)(cb + j * 16 + l16) * 2] = (__bf16)acc[i][j][rg2];
            } else {
#pragma unroll
                for (int j = 0; j < NT; ++j)
                    C[(size_t)gr * BNtot + cb + j * 16 + l16] = (__bf16)acc[i][j][rg2];
            }
        }
    }
}

// ---------------------------------------------------------------------------
// Layer-1 pull aggregation: one wave per node. Block's 4 nodes share a
// contiguous meta range -> cooperative nontemporal load into LDS (windowed),
// inner loop reads meta via LDS broadcast; only gathers hit global.
// ---------------------------------------------------------------------------
__global__ void agg1_pull_kernel(const int* __restrict__ row_ptr, const int4* __restrict__ meta,
                                 const __bf16* __restrict__ hw1,
                                 const float2* __restrict__ dis,
                                 const float* __restrict__ b1,
                                 float* __restrict__ g_out, float* __restrict__ p_out, int n) {
    __shared__ i32x4 sm[AWIN];
    const int tid  = threadIdx.x;
    const int wave = tid >> 6;
    const int lane = tid & 63;
    const int c0   = blockIdx.x * 4;
    const int c    = c0 + wave;
    const int beg0 = row_ptr[c0];
    const int end3 = row_ptr[min(c0 + 4, n)];
    int beg = 0, end = 0;
    if (c < n) { beg = row_ptr[c]; end = row_ptr[c + 1]; }
    const int f2 = lane * 2;
    float sgx = 0.f, sgy = 0.f, spx = 0.f, spy = 0.f;

    for (int w = beg0; w < end3; w += AWIN) {
        const int cnt = min(AWIN, end3 - w);
        __syncthreads();
        for (int i = tid; i < cnt; i += 256)
            sm[i] = __builtin_nontemporal_load((const i32x4*)meta + w + i);
        __syncthreads();
        int t = max(beg, w);
        const int hi = min(end, w + cnt);
        for (; t + 8 <= hi; t += 8) {
            i32x4 m[8];
#pragma unroll
            for (int q = 0; q < 8; ++q) m[q] = sm[t - w + q];
            unsigned u[8];
#pragma unroll
            for (int q = 0; q < 8; ++q)
                u[q] = *(const unsigned*)(hw1 + ((size_t)(unsigned)m[q].x << 7) + f2);
#pragma unroll
            for (int q = 0; q < 8; ++q) {
                float2 h = bf2_to_f2(u[q]);
                float wg = __uint_as_float((unsigned)m[q].y);
                float wp = __uint_as_float((unsigned)m[q].z);
                sgx += wg * h.x; sgy += wg * h.y;
                spx += wp * h.x; spy += wp * h.y;
            }
        }
        if (t + 4 <= hi) {
            i32x4 m[4];
#pragma unroll
            for (int q = 0; q < 4; ++q) m[q] = sm[t - w + q];
            unsigned u[4];
#pragma unroll
            for (int q = 0; q < 4; ++q)
                u[q] = *(const unsigned*)(hw1 + ((size_t)(unsigned)m[q].x << 7) + f2);
#pragma unroll
            for (int q = 0; q < 4; ++q) {
                float2 h = bf2_to_f2(u[q]);
                float wg = __uint_as_float((unsigned)m[q].y);
                float wp = __uint_as_float((unsigned)m[q].z);
                sgx += wg * h.x; sgy += wg * h.y;
                spx += wp * h.x; spy += wp * h.y;
            }
            t += 4;
        }
        for (; t < hi; ++t) {
            i32x4 m0 = sm[t - w];
            float2 h0 = bf2_to_f2(*(const unsigned*)(hw1 + ((size_t)(unsigned)m0.x << 7) + f2));
            float wg0 = __uint_as_float((unsigned)m0.y);
            float wp0 = __uint_as_float((unsigned)m0.z);
            sgx += wg0 * h0.x; sgy += wg0 * h0.y;
            spx += wp0 * h0.x; spy += wp0 * h0.y;
        }
    }

    if (c < n) {
        float2 d = dis[c];
        size_t idx = ((size_t)c << 7) + f2;
        float2 hs = bf2_to_f2(*(const unsigned*)(hw1 + idx));
        float2 bv = *(const float2*)(b1 + f2);
        float gx = d.x * sgx + d.x * d.x * hs.x + bv.x;
        float gy = d.x * sgy + d.x * d.x * hs.y + bv.y;
        float px = d.y * spx + d.y * d.y * hs.x + bv.x;
        float py = d.y * spy + d.y * d.y * hs.y + bv.y;
        f32x2 go, po;
        go[0] = gx > 0.f ? gx : 0.f;  go[1] = gy > 0.f ? gy : 0.f;
        po[0] = px > 0.f ? px : 0.f;  po[1] = py > 0.f ? py : 0.f;
        __builtin_nontemporal_store(go, (f32x2*)(g_out + idx));
        __builtin_nontemporal_store(po, (f32x2*)(p_out + idx));
    }
}

// ---------------------------------------------------------------------------
// Layer-2 pull aggregation + self-loop + bias + softmax gate.
// hw2i layout: [n][64][2] bf16; LDS meta staging as agg1.
// ---------------------------------------------------------------------------
__global__ void agg2_final_kernel(const int* __restrict__ row_ptr, const int4* __restrict__ meta,
                                  const __bf16* __restrict__ hw2i,
                                  const float2* __restrict__ dis,
                                  const float* __restrict__ b2,
                                  const float* __restrict__ dense_w, const float* __restrict__ dense_b,
                                  float* __restrict__ out, int n) {
    __shared__ i32x4 sm[AWIN];
    const int tid  = threadIdx.x;
    const int wave = tid >> 6;
    const int f    = tid & 63;
    const int c0   = blockIdx.x * 4;
    const int c    = c0 + wave;
    const int beg0 = row_ptr[c0];
    const int end3 = row_ptr[min(c0 + 4, n)];
    int beg = 0, end = 0;
    if (c < n) { beg = row_ptr[c]; end = row_ptr[c + 1]; }
    const int f2 = f * 2;
    float sg = 0.f, sp = 0.f;

    for (int w = beg0; w < end3; w += AWIN) {
        const int cnt = min(AWIN, end3 - w);
        __syncthreads();
        for (int i = tid; i < cnt; i += 256)
            sm[i] = __builtin_nontemporal_load((const i32x4*)meta + w + i);
        __syncthreads();
        int t = max(beg, w);
        const int hi = min(end, w + cnt);
        for (; t + 8 <= hi; t += 8) {
            i32x4 m[8];
#pragma unroll
            for (int q = 0; q < 8; ++q) m[q] = sm[t - w + q];
            unsigned u[8];
#pragma unroll
            for (int q = 0; q < 8; ++q)
                u[q] = *(const unsigned*)(hw2i + ((size_t)(unsigned)m[q].x << 7) + f2);
#pragma unroll
            for (int q = 0; q < 8; ++q) {
                float2 g0 = bf2_to_f2(u[q]);
                sg += __uint_as_float((unsigned)m[q].y) * g0.x;
                sp += __uint_as_float((unsigned)m[q].z) * g0.y;
            }
        }
        if (t + 4 <= hi) {
            i32x4 m[4];
#pragma unroll
            for (int q = 0; q < 4; ++q) m[q] = sm[t - w + q];
            unsigned u[4];
#pragma unroll
            for (int q = 0; q < 4; ++q)
                u[q] = *(const unsigned*)(hw2i + ((size_t)(unsigned)m[q].x << 7) + f2);
#pragma unroll
            for (int q = 0; q < 4; ++q) {
                float2 g0 = bf2_to_f2(u[q]);
                sg += __uint_as_float((unsigned)m[q].y) * g0.x;
                sp += __uint_as_float((unsigned)m[q].z) * g0.y;
            }
            t += 4;
        }
        for (; t < hi; ++t) {
            i32x4 m0 = sm[t - w];
            float2 g0 = bf2_to_f2(*(const unsigned*)(hw2i + ((size_t)(unsigned)m0.x << 7) + f2));
            sg += __uint_as_float((unsigned)m0.y) * g0.x;
            sp += __uint_as_float((unsigned)m0.z) * g0.y;
        }
    }

    if (c < n) {
        float2 d = dis[c];
        float2 gps = bf2_to_f2(*(const unsigned*)(hw2i + ((size_t)c << 7) + f2));
        float bb = b2[f];
        float gv = d.x * sg + d.x * d.x * gps.x + bb;
        float pv = d.y * sp + d.y * d.y * gps.y + bb;
        float dwv = dense_w[f];
        float lg = gv * dwv, lp = pv * dwv;
#pragma unroll
        for (int off = 32; off > 0; off >>= 1) {
            lg += __shfl_xor(lg, off, 64);
            lp += __shfl_xor(lp, off, 64);
        }
        lg += dense_b[0];
        lp += dense_b[0];
        float m  = fmaxf(lg, lp);
        float eg = expf(lg - m), ep = expf(lp - m);
        float wgt = eg / (eg + ep);
        __builtin_nontemporal_store(wgt * gv + (1.0f - wgt) * pv, out + (size_t)c * OO + f);
    }
}

// ---------------------------------------------------------------------------
extern "C" void kernel_launch(void* const* d_in, const int* in_sizes, int n_in,
                              void* d_out, int out_size, void* d_ws, size_t ws_size,
                              hipStream_t stream) {
    const float* x    = (const float*)d_in[0];
    const int*   ei   = (const int*)d_in[1];
    const float* ppmi = (const float*)d_in[2];
    const float* W1   = (const float*)d_in[3];
    const float* b1   = (const float*)d_in[4];
    const float* W2   = (const float*)d_in[5];
    const float* b2   = (const float*)d_in[6];
    const float* dw   = (const float*)d_in[7];
    const float* db   = (const float*)d_in[8];
    float* out = (float*)d_out;

    const int n = in_sizes[0] / DD;       // 100000
    const int e = in_sizes[2];            // 1600000
    const int* row = ei;
    const int* col = ei + e;

    const int nb   = (n + BKT - 1) / BKT;   // buckets (<=256 required)
    const int nblk = (e + EPB - 1) / EPB;   // partition blocks (<=256 required)

    // ---- workspace layout ----
    float* ws      = (float*)d_ws;
    float2* dis    = (float2*)ws;                     // n float2
    __bf16* hw1    = (__bf16*)(ws + 2 * (size_t)n);   // n*128 bf16 (aliased as hw2i [n][64][2])
    float* g1      = (float*)(hw1 + (size_t)n * HH);  // n*128 f32 (tmp_col aliases: int4[e])
    float* p1      = g1 + (size_t)n * HH;             // n*128 f32 (tmp_row aliases: int2[e])
    int4* csr_meta = (int4*)(p1 + (size_t)n * HH);    // e int4 {src, wg, wp, 0}
    __bf16* bt1h   = (__bf16*)(csr_meta + e);         // DD*HH
    __bf16* bt1l   = bt1h + (size_t)DD * HH;
    __bf16* bt2h   = bt1l + (size_t)DD * HH;          // HH*OO
    __bf16* bt2l   = bt2h + (size_t)HH * OO;
    int* row_ptr   = (int*)(bt2l + (size_t)HH * OO);  // n+1
    int* cnt_col   = row_ptr + (n + 1);               // nblk*nb
    int* base_col  = cnt_col + (size_t)nblk * nb;     // nblk*nb
    int* cnt_row   = base_col + (size_t)nblk * nb;    // nblk*nb
    int* base_row  = cnt_row + (size_t)nblk * nb;     // nblk*nb
    int* bb_col    = base_row + (size_t)nblk * nb;    // nb
    int* tot_col   = bb_col + nb;                     // nb
    int* bb_row    = tot_col + nb;                    // nb
    int* tot_row   = bb_row + nb;                     // nb
    int4* tmp_col  = (int4*)g1;                       // e (alias, dead before agg1 writes g1)
    int2* tmp_row  = (int2*)p1;                       // e (alias, dead before agg1 writes p1)
    __bf16* hw2i   = hw1;                             // [n][64][2] bf16 (hw1 dead after agg1)

    const int T = 256;

    // ---- partition pipeline (LDS atomics only, fully parallel scans) ----
    part_count_kernel<<<nblk, 512, 0, stream>>>(row, col, e, nb, cnt_col, cnt_row);
    scan_blocks_kernel<<<2 * nb, T, 0, stream>>>(cnt_col, cnt_row, base_col, base_row,
                                                 tot_col, tot_row, nblk, nb);
    add_bases_kernel<<<2 * nb, T, 0, stream>>>(base_col, base_row, tot_col, tot_row,
                                               bb_col, bb_row, row_ptr, n, e, nblk, nb);
    part_scatter_kernel<<<nblk, 512, 0, stream>>>(row, col, ppmi, base_col, base_row,
                                                  tmp_col, tmp_row, e, nb);
    deg_bucket_kernel<<<nb, 512, 0, stream>>>(tmp_row, bb_row, tot_row, dis, n);
    csr_bucket_kernel<<<nb, BKT, 0, stream>>>(tmp_col, bb_col, tot_col, dis,
                                              row_ptr, csr_meta, n);

    // ---- weight prep (fused) ----
    conv_w_kernel<<<(DD * HH + HH * OO + T - 1) / T, T, 0, stream>>>(W1, bt1h, bt1l,
                                                                     W2, bt2h, bt2l);

    // ---- network ----
    {
        int nrg = (n + 255) / 256;             // row-groups, 2 col-groups
        mfma_gemm_ldsb_kernel<64, 256, false><<<nrg * 2, 512, 0, stream>>>(
            x, bt1h, bt1l, hw1, n, 0, 2, HH);
    }
    agg1_pull_kernel<<<(n + 3) / 4, 256, 0, stream>>>(row_ptr, csr_meta, hw1, dis, b1, g1, p1, n);
    {
        int nrg = (2 * n + 255) / 256;         // row-groups, 1 col-group
        mfma_gemm_ldsb_kernel<64, 128, true><<<nrg, 512, 0, stream>>>(
            g1, bt2h, bt2l, hw2i, 2 * n, n, 1, OO);
    }
    agg2_final_kernel<<<(n + 3) / 4, 256, 0, stream>>>(row_ptr, csr_meta, hw2i, dis,
                                                       b2, dw, db, out, n);
}